// Round 8
// baseline (146.017 us; speedup 1.0000x reference)
//
#include <hip/hip_runtime.h>
#include <math.h>

// Causal flash attention, B=2 H=16 S=2048 D=64, fp32 in/out, bf16 MFMA compute.
// R8 = R7 with corrected v_permlane32_swap_b32 orientation (CDNA4 ISA: swap
// odd row of vdst with even row of src => swap(a,b) -> r0={a.lo||b.lo},
// r1={a.hi||b.hi}). P C-layout -> A-layout exchange on the VALU pipe; no
// ds_bpermute. Rest as R6/R7: 64 q/wave, paired q-blocks split-4 (512 uniform
// blocks), global_load_lds dbuf staging, pre-scaled bf16 Q, ones-MFMA row-sum
// l, packed-bf16 partial O; combine O=(Sum O_z)/(Sum l_z).

constexpr int kS   = 2048;
constexpr int kD   = 64;
constexpr int kBH  = 32;
constexpr int kPadP = 72;   // prep-kernel LDS pad only

typedef short short8 __attribute__((ext_vector_type(8)));
typedef float float4v __attribute__((ext_vector_type(4)));
typedef float float16v __attribute__((ext_vector_type(16)));
typedef unsigned int u32;
typedef unsigned short u16;

static __device__ inline u16 f2bf(float f) {
  union { float f; unsigned u; } v; v.f = f;
  unsigned r = v.u + 0x7FFF + ((v.u >> 16) & 1);   // RNE
  return (u16)(r >> 16);
}

static __device__ inline short8 pack8(float4v a, float4v b) {
  short8 r;
  r[0] = (short)f2bf(a[0]); r[1] = (short)f2bf(a[1]);
  r[2] = (short)f2bf(a[2]); r[3] = (short)f2bf(a[3]);
  r[4] = (short)f2bf(b[0]); r[5] = (short)f2bf(b[1]);
  r[6] = (short)f2bf(b[2]); r[7] = (short)f2bf(b[3]);
  return r;
}

static __device__ inline void async_cp16(const void* g, void* l) {
  __builtin_amdgcn_global_load_lds(
      (const __attribute__((address_space(1))) u32*)g,
      (__attribute__((address_space(3))) u32*)l, 16, 0, 0);
}

// lo = {pga.lo(lanes0-31) || pgb.lo(->lanes32-63)};  hi = {pga.hi(->lanes0-31) || pgb.hi}.
static __device__ inline void xhalf(u32 pga, u32 pgb, u32& lo, u32& hi) {
#if __has_builtin(__builtin_amdgcn_permlane32_swap)
  auto r = __builtin_amdgcn_permlane32_swap(pga, pgb, false, false);
  lo = r[0];   // new_vdst = {pga.lo || pgb.lo}
  hi = r[1];   // new_src  = {pga.hi || pgb.hi}
#else
  const u32 ea = (u32)__shfl_xor((int)pga, 32);
  const u32 eb = (u32)__shfl_xor((int)pgb, 32);
  const bool top = (threadIdx.x & 32) != 0;
  lo = top ? eb : pga;
  hi = top ? pgb : ea;
#endif
}

// ---- prepass: Q -> scaled bf16 [bh][s][d]; K -> bf16 [bh][s][d];
//               V -> bf16 transposed [bh][d][s] ----
__global__ __launch_bounds__(256)
void prep_kernel(const float* __restrict__ Q, const float* __restrict__ K,
                 const float* __restrict__ V,
                 u16* __restrict__ Qb, u16* __restrict__ Kb, u16* __restrict__ VT) {
  __shared__ u16 tile[64 * kPadP];
  const int tid = threadIdx.x;
  const int bh = blockIdx.y, st = blockIdx.x;
  const size_t ibase = (size_t)bh * kS * kD + (size_t)st * 64 * kD;
  const int r  = tid >> 2;
  const int c0 = (tid & 3) * 16;
  {
    const float scl = 0.125f * 1.44269504089f;   // 1/sqrt(64) * log2(e)
    const float* qp = Q + ibase + (size_t)r * kD + c0;
    float4v a = *(const float4v*)(qp);
    float4v b = *(const float4v*)(qp + 4);
    float4v c = *(const float4v*)(qp + 8);
    float4v d = *(const float4v*)(qp + 12);
    #pragma unroll
    for (int i = 0; i < 4; ++i) { a[i] *= scl; b[i] *= scl; c[i] *= scl; d[i] *= scl; }
    u16* dst = Qb + ibase + (size_t)r * kD + c0;
    *(short8*)dst       = pack8(a, b);
    *(short8*)(dst + 8) = pack8(c, d);
  }
  {
    const float* kp = K + ibase + (size_t)r * kD + c0;
    float4v a = *(const float4v*)(kp);
    float4v b = *(const float4v*)(kp + 4);
    float4v c = *(const float4v*)(kp + 8);
    float4v d = *(const float4v*)(kp + 12);
    u16* dst = Kb + ibase + (size_t)r * kD + c0;
    *(short8*)dst       = pack8(a, b);
    *(short8*)(dst + 8) = pack8(c, d);
  }
  {
    const float* vp = V + ibase + (size_t)r * kD + c0;
    float4v a = *(const float4v*)(vp);
    float4v b = *(const float4v*)(vp + 4);
    float4v c = *(const float4v*)(vp + 8);
    float4v d = *(const float4v*)(vp + 12);
    u16* t = &tile[r * kPadP + c0];
    *(short8*)t       = pack8(a, b);
    *(short8*)(t + 8) = pack8(c, d);
  }
  __syncthreads();
  {
    const int dd = tid >> 2;
    const int s0 = (tid & 3) * 16;
    short8 w0, w1;
    #pragma unroll
    for (int i = 0; i < 8; ++i) {
      w0[i] = (short)tile[(s0 + i) * kPadP + dd];
      w1[i] = (short)tile[(s0 + 8 + i) * kPadP + dd];
    }
    u16* vdst = VT + (size_t)bh * kD * kS + (size_t)dd * kS + st * 64 + s0;
    *(short8*)vdst       = w0;
    *(short8*)(vdst + 8) = w1;
  }
}

// ---- main flash kernel ----
__global__ __launch_bounds__(256, 2)
void fattn_kernel(const u16* __restrict__ Qb, const u16* __restrict__ Kb,
                  const u16* __restrict__ VT,
                  u32* __restrict__ O0, u32* __restrict__ O1,
                  u32* __restrict__ O2, u32* __restrict__ O3,
                  float* __restrict__ Lp) {
  // swizzled: 16B chunk c of row r stored at linear chunk r*8 + (c^(r&7))
  __shared__ __align__(16) u16 ldsK[2][4096];   // [buf][key 0..63][d]
  __shared__ __align__(16) u16 ldsV[2][4096];   // [buf][d 0..63][key]

  const int tid  = threadIdx.x;
  const int wave = tid >> 6;
  const int lane = tid & 63;
  const int l31  = lane & 31;
  const int h    = lane >> 5;

  const int bh = blockIdx.y;
  const int p  = blockIdx.x >> 2;
  const int z  = blockIdx.x & 3;
  const int qiA = p, qiB = 7 - p;
  const int nA  = 4 * p + 4;

  const size_t base  = (size_t)bh * kS * kD;
  const size_t vbase = (size_t)bh * kD * kS;

  const int lr  = lane >> 3;
  const int cxl = (lane & 7) ^ lr;
  const int offK0 = lr * 64   + cxl * 8;
  const int offV0 = lr * 2048 + cxl * 8;
  const unsigned hs16 = ((unsigned)(h ^ (l31 & 7))) * 16;

  u32* Od = (z == 0) ? O0 : (z == 1) ? O1 : (z == 2) ? O2 : O3;
  const int cB = 9 * z;
  const int cE = cB + 9;

  short8 ones;
  #pragma unroll
  for (int i = 0; i < 8; ++i) ones[i] = (short)0x3F80;

  int par = 0;
  for (int seg = 0; seg < 2; ++seg) {
    const int qi = seg ? qiB : qiA;
    int tb, te;
    if (seg == 0) { tb = min(cB, nA); te = min(cE, nA); }
    else          { tb = max(cB, nA) - nA; te = max(cE, nA) - nA; }
    const int wq0 = qi * 256 + wave * 64;

    // Q fragments (pre-scaled bf16): set g covers q = wq0+32g+l31
    short8 qf[2][4];
    #pragma unroll
    for (int g = 0; g < 2; ++g) {
      const u16* qp = Qb + base + (size_t)(wq0 + 32 * g + l31) * kD + h * 8;
      #pragma unroll
      for (int dk = 0; dk < 4; ++dk) qf[g][dk] = *(const short8*)(qp + dk * 16);
    }

    float16v acc[2][2], lacc[2];
    #pragma unroll
    for (int g = 0; g < 2; ++g) {
      #pragma unroll
      for (int i = 0; i < 16; ++i) { acc[g][0][i] = 0.f; acc[g][1][i] = 0.f; lacc[g][i] = 0.f; }
    }

    if (tb < te) {
      {
        const u16* kg0 = Kb + base + (size_t)tb * 4096;
        const u16* vg0 = VT + vbase + tb * 64;
        const int b = par & 1;
        #pragma unroll
        for (int j = 0; j < 2; ++j) {
          const int g = wave + 4 * j;
          async_cp16(kg0 + g * 512 + offK0,           &ldsK[b][g * 512]);
          async_cp16(vg0 + (size_t)g * 16384 + offV0, &ldsV[b][g * 512]);
        }
      }
      for (int t = tb; t < te; ++t, ++par) {
        __syncthreads();
        if (t + 1 < te) {
          const u16* kg0 = Kb + base + (size_t)(t + 1) * 4096;
          const u16* vg0 = VT + vbase + (t + 1) * 64;
          const int b = (par + 1) & 1;
          #pragma unroll
          for (int j = 0; j < 2; ++j) {
            const int g = wave + 4 * j;
            async_cp16(kg0 + g * 512 + offK0,           &ldsK[b][g * 512]);
            async_cp16(vg0 + (size_t)g * 16384 + offV0, &ldsV[b][g * 512]);
          }
        }
        const char* KB = (const char*)ldsK[par & 1];
        const char* VB = (const char*)ldsV[par & 1];
        #pragma unroll
        for (int kt32 = 0; kt32 < 2; ++kt32) {
          const int ktb = t * 64 + kt32 * 32;
          if (ktb > wq0 + 63) break;        // above both sets' diagonals
          const bool live0 = (ktb <= wq0 + 31);

          // K / V fragments (shared by both q-sets)
          const char* krow = KB + (kt32 * 32 + l31) * 128;
          short8 kf[4];
          #pragma unroll
          for (int dk = 0; dk < 4; ++dk)
            kf[dk] = *(const short8*)(krow + (((unsigned)(dk * 32)) ^ hs16));
          short8 vf[4];
          #pragma unroll
          for (int c = 0; c < 2; ++c) {
            const unsigned coff = ((unsigned)((kt32 * 4 + 2 * c) * 16)) ^ hs16;
            vf[2 * c]     = *(const short8*)(VB + l31 * 128 + coff);
            vf[2 * c + 1] = *(const short8*)(VB + (32 + l31) * 128 + coff);
          }

          // ---- S^T = K * Q^T for both sets, issued back-to-back ----
          float16v s0, s1;
          #pragma unroll
          for (int i = 0; i < 16; ++i) { s0[i] = 0.f; s1[i] = 0.f; }
          if (live0) {
            #pragma unroll
            for (int dk = 0; dk < 4; ++dk)
              s0 = __builtin_amdgcn_mfma_f32_32x32x16_bf16(kf[dk], qf[0][dk], s0, 0, 0, 0);
          }
          #pragma unroll
          for (int dk = 0; dk < 4; ++dk)
            s1 = __builtin_amdgcn_mfma_f32_32x32x16_bf16(kf[dk], qf[1][dk], s1, 0, 0, 0);

          // ---- per set: mask, exp2, pack, cross-half swap, PV ----
          #pragma unroll
          for (int g = 0; g < 2; ++g) {
            if (g == 0 && !live0) continue;
            float16v& s = g ? s1 : s0;

            if (ktb == wq0 + 32 * g) {     // diagonal subtile of this set
              const int qg = wq0 + 32 * g + l31;
              #pragma unroll
              for (int r = 0; r < 16; ++r) {
                const int kg = ktb + (r & 3) + 8 * (r >> 2) + 4 * h;
                if (kg > qg) s[r] = -1e30f;
              }
            }

            u32 pk[8];
            #pragma unroll
            for (int g2 = 0; g2 < 4; ++g2) {
              const u32 u0 = __float_as_uint(__builtin_amdgcn_exp2f(s[4 * g2 + 0]));
              const u32 u1 = __float_as_uint(__builtin_amdgcn_exp2f(s[4 * g2 + 1]));
              const u32 u2 = __float_as_uint(__builtin_amdgcn_exp2f(s[4 * g2 + 2]));
              const u32 u3 = __float_as_uint(__builtin_amdgcn_exp2f(s[4 * g2 + 3]));
              pk[2 * g2]     = __builtin_amdgcn_perm(u1, u0, 0x07060302u);
              pk[2 * g2 + 1] = __builtin_amdgcn_perm(u3, u2, 0x07060302u);
            }

            #pragma unroll
            for (int c = 0; c < 2; ++c) {
              const int ga = 4 * c, gb = 4 * c + 2;
              union { u32 u[4]; short8 s8; } pf;
              xhalf(pk[ga],     pk[gb],     pf.u[0], pf.u[2]);
              xhalf(pk[ga + 1], pk[gb + 1], pf.u[1], pf.u[3]);
              acc[g][0] = __builtin_amdgcn_mfma_f32_32x32x16_bf16(pf.s8, vf[2 * c],     acc[g][0], 0, 0, 0);
              acc[g][1] = __builtin_amdgcn_mfma_f32_32x32x16_bf16(pf.s8, vf[2 * c + 1], acc[g][1], 0, 0, 0);
              lacc[g]   = __builtin_amdgcn_mfma_f32_32x32x16_bf16(pf.s8, ones,          lacc[g],   0, 0, 0);
            }
          }
        }
      }
    }

    // ---- epilogue: packed-bf16 partial O + fp32 partial l ----
    #pragma unroll
    for (int g = 0; g < 2; ++g) {
      #pragma unroll
      for (int r = 0; r < 16; ++r) {
        const int row = (r & 3) + 8 * (r >> 2) + 4 * h;
        const u32 w = (u32)f2bf(acc[g][0][r]) | ((u32)f2bf(acc[g][1][r]) << 16);
        Od[((size_t)bh * kS + wq0 + 32 * g + row) * 32 + l31] = w;
      }
      if (l31 == 0) {
        #pragma unroll
        for (int r = 0; r < 16; ++r) {
          const int row = (r & 3) + 8 * (r >> 2) + 4 * h;
          Lp[(size_t)z * kBH * kS + (size_t)bh * kS + wq0 + 32 * g + row] = lacc[g][r];
        }
      }
    }
  }
}

// ---- combine: O = (Sum O_z) / (Sum l_z); partials are packed bf16 (d, d+32) ----
__global__ __launch_bounds__(256)
void combine_kernel(const u32* __restrict__ O0, const u32* __restrict__ O1,
                    const u32* __restrict__ O2, const u32* __restrict__ O3,
                    const float* __restrict__ Lp, float* __restrict__ O) {
  const int idx = blockIdx.x * 256 + threadIdx.x;   // row*32 + j
  const int row = idx >> 5;
  const int j   = idx & 31;
  const int N = kBH * kS;
  const float l = Lp[row] + Lp[N + row] + Lp[2 * N + row] + Lp[3 * N + row];
  const float inv = 1.f / l;
  const u32 a = O0[idx], b = O1[idx], c = O2[idx], d = O3[idx];
  const float lo = __uint_as_float(a << 16) + __uint_as_float(b << 16)
                 + __uint_as_float(c << 16) + __uint_as_float(d << 16);
  const float hi = __uint_as_float(a & 0xFFFF0000u) + __uint_as_float(b & 0xFFFF0000u)
                 + __uint_as_float(c & 0xFFFF0000u) + __uint_as_float(d & 0xFFFF0000u);
  float* op = O + (size_t)row * kD;
  op[j]      = lo * inv;
  op[j + 32] = hi * inv;
}

extern "C" void kernel_launch(void* const* d_in, const int* in_sizes, int n_in,
                              void* d_out, int out_size, void* d_ws, size_t ws_size,
                              hipStream_t stream) {
  const float* Q = (const float*)d_in[0];
  const float* K = (const float*)d_in[1];
  const float* V = (const float*)d_in[2];
  float* O = (float*)d_out;

  const size_t nKV = (size_t)kBH * kS * kD;      // 4.19M elems
  u16* Qb = (u16*)d_ws;                          // 8.39 MB
  u16* Kb = Qb + nKV;                            // 8.39 MB
  u16* VT = Kb + nKV;                            // 8.39 MB
  u32* O0 = (u32*)(VT + nKV);                    // 8.39 MB each (packed bf16 pairs)
  u32* O1 = O0 + nKV / 2;
  u32* O2 = O1 + nKV / 2;
  u32* O3 = O2 + nKV / 2;
  float* Lp = (float*)(O3 + nKV / 2);            // 1.05 MB

  dim3 gprep(kS / 64, kBH);
  prep_kernel<<<gprep, 256, 0, stream>>>(Q, K, V, Qb, Kb, VT);
  dim3 grid(16, kBH);    // 4 pairs x 4 z, 32 bh
  fattn_kernel<<<grid, 256, 0, stream>>>(Qb, Kb, VT, O0, O1, O2, O3, Lp);
  combine_kernel<<<(int)(kBH * kS * 32 / 256), 256, 0, stream>>>(O0, O1, O2, O3, Lp, O);
}